// Round 2
// baseline (1066.776 us; speedup 1.0000x reference)
//
#include <hip/hip_runtime.h>
#include <cstdint>
#include <math.h>

#define EMB 128
#define CHUNK 64

// starts[b] = first token index with segment_ids[i] >= b  (segment_ids sorted).
// starts[B] = T. Handles empty segments naturally.
__global__ void seg_starts_kernel(const int* __restrict__ seg, int T, int B,
                                  int* __restrict__ starts) {
    int b = blockIdx.x * blockDim.x + threadIdx.x;
    if (b > B) return;
    int lo = 0, hi = T;
    while (lo < hi) {
        int mid = (lo + hi) >> 1;
        if (seg[mid] < b) lo = mid + 1; else hi = mid;
    }
    starts[b] = lo;
}

__global__ __launch_bounds__(256, 4) void attn_kernel(
    const float* __restrict__ value, const float* __restrict__ key,
    const int* __restrict__ starts, const float* __restrict__ fingerprint,
    const float* __restrict__ w, float* __restrict__ out)
{
    __shared__ float key_lds[CHUNK * EMB];   // 32 KB: staged key chunk
    __shared__ float s_lds[CHUNK];           // raw scores
    __shared__ float e_lds[CHUNK];           // exp(score - m_new)
    __shared__ float dwf_lds[EMB];           // diag(w)*fingerprint/sqrt(E)
    __shared__ float red2[2];                // m_new, chunk_sum

    const int b   = blockIdx.x;
    const int tid = threadIdx.x;
    const int s0  = starts[b];
    const int s1  = starts[b + 1];
    const int len = s1 - s0;

    if (tid < EMB)
        dwf_lds[tid] = w[tid * EMB + tid] * fingerprint[tid] * 0.08838834764831845f; // 1/sqrt(128)
    __syncthreads();

    const int lane = tid & 63;
    const int wv   = tid >> 6;
    const float dlo = dwf_lds[lane];
    const float dhi = dwf_lds[lane + 64];

    float acc   = 0.0f;       // thread tid owns output column tid (0..255)
    float m     = -INFINITY;  // running max (uniform across block)
    float denom = 0.0f;       // running sum of exp (uniform across block)

    for (int o = 0; o < len; o += CHUNK) {
        const int cl = min(CHUNK, len - o);

        // ---- stage key chunk into LDS (coalesced float4) ----
        const float4* kbase = (const float4*)(key + (size_t)(s0 + o) * EMB);
        const int n4 = cl * (EMB / 4);
        for (int f = tid; f < n4; f += 256)
            ((float4*)key_lds)[f] = kbase[f];
        __syncthreads();

        // ---- scores: wave-per-token, butterfly reduce ----
        for (int r = 0; r < CHUNK / 4; ++r) {
            int t = wv + 4 * r;
            if (t < cl) {
                float sc = key_lds[t * EMB + lane] * dlo
                         + key_lds[t * EMB + lane + 64] * dhi;
                #pragma unroll
                for (int off = 32; off; off >>= 1) sc += __shfl_xor(sc, off);
                if (lane == 0) s_lds[t] = sc;
            } else {
                if (lane == 0) s_lds[t] = -INFINITY;   // pad tail
            }
        }
        __syncthreads();

        // ---- online-softmax chunk update (wave 0 computes, all consume) ----
        const float m_old = m;
        if (wv == 0) {
            float s  = s_lds[lane];
            float mx = s;
            #pragma unroll
            for (int off = 32; off; off >>= 1) mx = fmaxf(mx, __shfl_xor(mx, off));
            float m_new = fmaxf(m_old, mx);
            float e = (s > -INFINITY) ? __expf(s - m_new) : 0.0f;
            e_lds[lane] = e;
            float ss = e;
            #pragma unroll
            for (int off = 32; off; off >>= 1) ss += __shfl_xor(ss, off);
            if (lane == 0) { red2[0] = m_new; red2[1] = ss; }
        }
        __syncthreads();
        const float m_new = red2[0];
        const float csum  = red2[1];
        const float alpha = (m_old > -INFINITY) ? __expf(m_old - m_new) : 0.0f;
        acc   = acc * alpha;
        denom = denom * alpha + csum;
        m     = m_new;

        // ---- accumulate: cols 0..127 from value (global, coalesced),
        //      cols 128..255 from key (LDS, already staged) ----
        if (tid < 128) {
            const float* vcol = value + (size_t)(s0 + o) * EMB + tid;
            #pragma unroll 4
            for (int t = 0; t < cl; ++t)
                acc = fmaf(e_lds[t], vcol[(size_t)t * EMB], acc);
        } else {
            const float* kcol = key_lds + (tid - 128);
            #pragma unroll 4
            for (int t = 0; t < cl; ++t)
                acc = fmaf(e_lds[t], kcol[t * EMB], acc);
        }
        __syncthreads();   // before next chunk overwrites key_lds/e_lds
    }

    const float r = (denom > 0.0f) ? acc / denom : 0.0f;
    out[(size_t)b * (2 * EMB) + tid] = r;
}

extern "C" void kernel_launch(void* const* d_in, const int* in_sizes, int n_in,
                              void* d_out, int out_size, void* d_ws, size_t ws_size,
                              hipStream_t stream) {
    const float* value = (const float*)d_in[0];
    const float* key   = (const float*)d_in[1];
    const int*   seg   = (const int*)d_in[2];
    const float* fp    = (const float*)d_in[3];
    const float* w     = (const float*)d_in[4];
    float* out = (float*)d_out;

    const int T = in_sizes[2];
    const int B = out_size / (2 * EMB);

    int* starts = (int*)d_ws;  // (B+1) ints, recomputed every call (ws is poisoned)

    const int nb = (B + 1 + 255) / 256;
    seg_starts_kernel<<<nb, 256, 0, stream>>>(seg, T, B, starts);
    attn_kernel<<<B, 256, 0, stream>>>(value, key, starts, fp, w, out);
}